// Round 1
// baseline (1459.606 us; speedup 1.0000x reference)
//
#include <hip/hip_runtime.h>

#define NTHREADS 256
#define HID 96
#define INF 64
#define OUTF 16
#define NLAYERS 16

// ---------------- preprocessing ----------------
__global__ void k_init(int* __restrict__ deg, int* __restrict__ cnt,
                       int* __restrict__ cur, int n) {
  int i = blockIdx.x * NTHREADS + threadIdx.x;
  if (i < n) { deg[i] = 1; cnt[i] = 0; cur[i] = 0; }  // deg=1 accounts for self-loop
}

__global__ void k_count(const int* __restrict__ row, const int* __restrict__ col,
                        int* __restrict__ deg, int* __restrict__ cnt, int e) {
  int i = blockIdx.x * NTHREADS + threadIdx.x;
  if (i < e) {
    atomicAdd(deg + col[i], 1);   // degree counted over col (+ self-loop via init)
    atomicAdd(cnt + row[i], 1);   // CSR row counts (self-loops handled separately)
  }
}

__global__ void k_dis(const int* __restrict__ deg, float* __restrict__ dis,
                      float* __restrict__ selfval, int n) {
  int i = blockIdx.x * NTHREADS + threadIdx.x;
  if (i < n) {
    float d = (float)deg[i];
    dis[i] = rsqrtf(d);
    selfval[i] = 1.0f / d;        // dis[i]^2 for the self-loop edge
  }
}

__global__ void k_scan1(const int* __restrict__ cnt, int* __restrict__ rp,
                        int* __restrict__ bsum, int n) {
  __shared__ int sh[NTHREADS];
  int t = threadIdx.x;
  int i = blockIdx.x * NTHREADS + t;
  int v = (i < n) ? cnt[i] : 0;
  sh[t] = v;
  __syncthreads();
  for (int ofs = 1; ofs < NTHREADS; ofs <<= 1) {
    int u = (t >= ofs) ? sh[t - ofs] : 0;
    __syncthreads();
    sh[t] += u;
    __syncthreads();
  }
  if (i < n) rp[i] = sh[t] - v;                    // exclusive prefix within block
  if (t == NTHREADS - 1) bsum[blockIdx.x] = sh[t]; // block total
}

__global__ void k_scan2(int* __restrict__ bsum, int nb) {  // nb <= 256
  __shared__ int sh[NTHREADS];
  int t = threadIdx.x;
  int v = (t < nb) ? bsum[t] : 0;
  sh[t] = v;
  __syncthreads();
  for (int ofs = 1; ofs < NTHREADS; ofs <<= 1) {
    int u = (t >= ofs) ? sh[t - ofs] : 0;
    __syncthreads();
    sh[t] += u;
    __syncthreads();
  }
  if (t < nb) bsum[t] = sh[t] - v;                 // exclusive
}

__global__ void k_scan3(int* __restrict__ rp, const int* __restrict__ bsum,
                        int n, int etot) {
  int i = blockIdx.x * NTHREADS + threadIdx.x;
  if (i < n) rp[i] += bsum[blockIdx.x];
  if (i == 0) rp[n] = etot;
}

__global__ void k_scatter(const int* __restrict__ row, const int* __restrict__ col,
                          const int* __restrict__ rp, int* __restrict__ cur,
                          const float* __restrict__ dis, int* __restrict__ col_s,
                          float* __restrict__ val_s, int e) {
  int i = blockIdx.x * NTHREADS + threadIdx.x;
  if (i < e) {
    int r = row[i], c = col[i];
    int p = rp[r] + atomicAdd(cur + r, 1);
    col_s[p] = c;
    val_s[p] = dis[r] * dis[c];
  }
}

// w'_l = (1-beta_l) I + beta_l * w_l   (identity-mapping fold)
__global__ void k_wprime(const float* __restrict__ cw, float* __restrict__ wp) {
  int l = blockIdx.y;
  int idx = blockIdx.x * NTHREADS + threadIdx.x;   // 0..9215
  int k = idx / HID, f = idx % HID;
  float beta = logf(0.5f / (float)(l + 1) + 1.0f);
  float v = beta * cw[l * HID * HID + idx];
  if (k == f) v += 1.0f - beta;
  wp[l * HID * HID + idx] = v;
}

// ---------------- h0 = relu(x @ w0^T + b0) ----------------
__global__ __launch_bounds__(NTHREADS) void k_lin0(
    const float* __restrict__ x, const float* __restrict__ w0,
    const float* __restrict__ b0, float* __restrict__ out, int n) {
  __shared__ float wl[INF * HID];   // wl[c][h], stride 96
  __shared__ float xT[INF * 68];    // xT[c][r], padded stride 68
  int tid = threadIdx.x;
#pragma unroll
  for (int i = 0; i < 6; ++i) {     // w0: 96x64 = 1536 float4
    int idx = tid + i * NTHREADS;
    int hrow = idx / 16, q = idx % 16;
    float4 v = *(const float4*)(w0 + hrow * INF + q * 4);
    wl[(q * 4 + 0) * HID + hrow] = v.x;
    wl[(q * 4 + 1) * HID + hrow] = v.y;
    wl[(q * 4 + 2) * HID + hrow] = v.z;
    wl[(q * 4 + 3) * HID + hrow] = v.w;
  }
  int r0 = blockIdx.x * 64;
#pragma unroll
  for (int i = 0; i < 4; ++i) {     // x tile: 64x64 = 1024 float4
    int idx = tid + i * NTHREADS;
    int r = idx / 16, q = idx % 16;
    int gr = r0 + r;
    float4 v = make_float4(0.f, 0.f, 0.f, 0.f);
    if (gr < n) v = *(const float4*)(x + (size_t)gr * INF + q * 4);
    xT[(q * 4 + 0) * 68 + r] = v.x;
    xT[(q * 4 + 1) * 68 + r] = v.y;
    xT[(q * 4 + 2) * 68 + r] = v.z;
    xT[(q * 4 + 3) * 68 + r] = v.w;
  }
  __syncthreads();
  int rg = tid & 15, cg = tid >> 4;
  float acc[4][6];
#pragma unroll
  for (int i = 0; i < 4; ++i)
#pragma unroll
    for (int j = 0; j < 6; ++j) acc[i][j] = 0.f;
#pragma unroll 4
  for (int k = 0; k < INF; ++k) {
    float4 s4 = *(const float4*)(xT + k * 68 + rg * 4);
    const float2* w2 = (const float2*)(wl + k * HID + cg * 6);
    float2 wa = w2[0], wb = w2[1], wc = w2[2];
    float wv[6] = {wa.x, wa.y, wb.x, wb.y, wc.x, wc.y};
    float sv[4] = {s4.x, s4.y, s4.z, s4.w};
#pragma unroll
    for (int i = 0; i < 4; ++i)
#pragma unroll
      for (int j = 0; j < 6; ++j) acc[i][j] = fmaf(sv[i], wv[j], acc[i][j]);
  }
  float bb[6];
#pragma unroll
  for (int j = 0; j < 6; ++j) bb[j] = b0[cg * 6 + j];
#pragma unroll
  for (int i = 0; i < 4; ++i) {
    int gr = r0 + rg * 4 + i;
    if (gr < n) {
      float* o = out + (size_t)gr * HID + cg * 6;
#pragma unroll
      for (int j = 0; j < 6; ++j) o[j] = fmaxf(acc[i][j] + bb[j], 0.f);
    }
  }
}

// ---------------- SpMM + residual: s = 0.9*(A_hat h) + 0.1*x0 ----------------
// one 32-lane half-wave per row; lane covers features {sub, sub+32, sub+64}
__global__ __launch_bounds__(NTHREADS) void k_spmm(
    const float* __restrict__ hin, const float* __restrict__ x0,
    float* __restrict__ sout, const int* __restrict__ rp,
    const int* __restrict__ col_s, const float* __restrict__ val_s,
    const float* __restrict__ selfval, int n) {
  int sub = threadIdx.x & 31;
  int r = blockIdx.x * 8 + (threadIdx.x >> 5);
  if (r >= n) return;
  const float* hr = hin + (size_t)r * HID;
  float svv = selfval[r];
  float a0 = svv * hr[sub];
  float a1 = svv * hr[sub + 32];
  float a2 = svv * hr[sub + 64];
  int e0 = rp[r], e1 = rp[r + 1];
  for (int ei = e0; ei < e1; ++ei) {
    int c = col_s[ei];
    float v = val_s[ei];
    const float* hc = hin + (size_t)c * HID;
    a0 = fmaf(v, hc[sub], a0);
    a1 = fmaf(v, hc[sub + 32], a1);
    a2 = fmaf(v, hc[sub + 64], a2);
  }
  size_t o = (size_t)r * HID;
  sout[o + sub]      = 0.9f * a0 + 0.1f * x0[o + sub];
  sout[o + sub + 32] = 0.9f * a1 + 0.1f * x0[o + sub + 32];
  sout[o + sub + 64] = 0.9f * a2 + 0.1f * x0[o + sub + 64];
}

// ---------------- in-place h = relu(s @ w'), 64 rows/block ----------------
__global__ __launch_bounds__(NTHREADS) void k_gemm(
    float* __restrict__ h, const float* __restrict__ wp, int n) {
  __shared__ float wl[HID * HID];   // [k][f]
  __shared__ float sT[HID * 68];    // [k][r], padded stride 68
  int tid = threadIdx.x;
  {
    const float4* wp4 = (const float4*)wp;
    float4* wl4 = (float4*)wl;
#pragma unroll
    for (int i = 0; i < 9; ++i) wl4[tid + i * NTHREADS] = wp4[tid + i * NTHREADS];
  }
  int r0 = blockIdx.x * 64;
#pragma unroll
  for (int i = 0; i < 6; ++i) {     // s tile: 64x96 = 1536 float4
    int idx = tid + i * NTHREADS;
    int r = idx / 24, q = idx % 24;
    int gr = r0 + r;
    float4 v = make_float4(0.f, 0.f, 0.f, 0.f);
    if (gr < n) v = *(const float4*)(h + (size_t)gr * HID + q * 4);
    sT[(q * 4 + 0) * 68 + r] = v.x;
    sT[(q * 4 + 1) * 68 + r] = v.y;
    sT[(q * 4 + 2) * 68 + r] = v.z;
    sT[(q * 4 + 3) * 68 + r] = v.w;
  }
  __syncthreads();
  int rg = tid & 15, cg = tid >> 4;
  float acc[4][6];
#pragma unroll
  for (int i = 0; i < 4; ++i)
#pragma unroll
    for (int j = 0; j < 6; ++j) acc[i][j] = 0.f;
#pragma unroll 4
  for (int k = 0; k < HID; ++k) {
    float4 s4 = *(const float4*)(sT + k * 68 + rg * 4);
    const float2* w2 = (const float2*)(wl + k * HID + cg * 6);
    float2 wa = w2[0], wb = w2[1], wc = w2[2];
    float wv[6] = {wa.x, wa.y, wb.x, wb.y, wc.x, wc.y};
    float sv4[4] = {s4.x, s4.y, s4.z, s4.w};
#pragma unroll
    for (int i = 0; i < 4; ++i)
#pragma unroll
      for (int j = 0; j < 6; ++j) acc[i][j] = fmaf(sv4[i], wv[j], acc[i][j]);
  }
#pragma unroll
  for (int i = 0; i < 4; ++i) {
    int gr = r0 + rg * 4 + i;
    if (gr < n) {
      float* o = h + (size_t)gr * HID + cg * 6;
#pragma unroll
      for (int j = 0; j < 6; ++j) o[j] = fmaxf(acc[i][j], 0.f);
    }
  }
}

// ---------------- out = h @ w1^T + b1 ----------------
__global__ __launch_bounds__(NTHREADS) void k_lin1(
    const float* __restrict__ h, const float* __restrict__ w1,
    const float* __restrict__ b1, float* __restrict__ out, int n) {
  __shared__ float hT[HID * 68];    // [k][r]
  __shared__ float w1l[HID * OUTF]; // [k][o]
  int tid = threadIdx.x;
#pragma unroll
  for (int i = 0; i < 6; ++i) {     // w1: 16x96 = 1536 floats
    int idx = tid + i * NTHREADS;
    int o = idx / HID, k = idx % HID;
    w1l[k * OUTF + o] = w1[idx];
  }
  int r0 = blockIdx.x * 64;
#pragma unroll
  for (int i = 0; i < 6; ++i) {     // h tile: 64x96 = 1536 float4
    int idx = tid + i * NTHREADS;
    int r = idx / 24, q = idx % 24;
    int gr = r0 + r;
    float4 v = make_float4(0.f, 0.f, 0.f, 0.f);
    if (gr < n) v = *(const float4*)(h + (size_t)gr * HID + q * 4);
    hT[(q * 4 + 0) * 68 + r] = v.x;
    hT[(q * 4 + 1) * 68 + r] = v.y;
    hT[(q * 4 + 2) * 68 + r] = v.z;
    hT[(q * 4 + 3) * 68 + r] = v.w;
  }
  __syncthreads();
  int r = tid & 63, og = tid >> 6;
  float acc[4] = {0.f, 0.f, 0.f, 0.f};
#pragma unroll 4
  for (int k = 0; k < HID; ++k) {
    float s = hT[k * 68 + r];
    float4 w4 = *(const float4*)(w1l + k * OUTF + og * 4);
    acc[0] = fmaf(s, w4.x, acc[0]);
    acc[1] = fmaf(s, w4.y, acc[1]);
    acc[2] = fmaf(s, w4.z, acc[2]);
    acc[3] = fmaf(s, w4.w, acc[3]);
  }
  int gr = r0 + r;
  if (gr < n) {
    float* op = out + (size_t)gr * OUTF + og * 4;
#pragma unroll
    for (int j = 0; j < 4; ++j) op[j] = acc[j] + b1[og * 4 + j];
  }
}

extern "C" void kernel_launch(void* const* d_in, const int* in_sizes, int n_in,
                              void* d_out, int out_size, void* d_ws, size_t ws_size,
                              hipStream_t stream) {
  const float* x  = (const float*)d_in[0];
  const int*   ei = (const int*)d_in[1];     // [2][E]: rows then cols
  const float* w0 = (const float*)d_in[2];
  const float* b0 = (const float*)d_in[3];
  const float* w1 = (const float*)d_in[4];
  const float* b1 = (const float*)d_in[5];
  const float* cw = (const float*)d_in[6];
  int n = in_sizes[0] / INF;    // 50000
  int e = in_sizes[1] / 2;      // 800000
  const int* row = ei;
  const int* col = ei + e;

  char* ws = (char*)d_ws;
  size_t off = 0;
  auto alloc = [&](size_t bytes) -> void* {
    void* p = (void*)(ws + off);
    off += (bytes + 255) & ~(size_t)255;
    return p;
  };
  float* x0   = (float*)alloc((size_t)n * HID * 4);
  float* hA   = (float*)alloc((size_t)n * HID * 4);
  float* hB   = (float*)alloc((size_t)n * HID * 4);
  float* wp   = (float*)alloc((size_t)NLAYERS * HID * HID * 4);
  int*   deg  = (int*)alloc((size_t)n * 4);
  float* dis  = (float*)alloc((size_t)n * 4);
  float* sv   = (float*)alloc((size_t)n * 4);
  int*   cnt  = (int*)alloc((size_t)n * 4);
  int*   cur  = (int*)alloc((size_t)n * 4);
  int*   rp   = (int*)alloc((size_t)(n + 1) * 4);
  int*   cols = (int*)alloc((size_t)e * 4);
  float* vals = (float*)alloc((size_t)e * 4);
  int*   bsum = (int*)alloc(1024 * 4);
  (void)ws_size; (void)n_in; (void)out_size;

  int nb  = (n + NTHREADS - 1) / NTHREADS;   // 196
  int ebl = (e + NTHREADS - 1) / NTHREADS;   // 3125
  int r64 = (n + 63) / 64;                   // 782

  k_init<<<nb, NTHREADS, 0, stream>>>(deg, cnt, cur, n);
  k_count<<<ebl, NTHREADS, 0, stream>>>(row, col, deg, cnt, e);
  k_dis<<<nb, NTHREADS, 0, stream>>>(deg, dis, sv, n);
  k_scan1<<<nb, NTHREADS, 0, stream>>>(cnt, rp, bsum, n);
  k_scan2<<<1, NTHREADS, 0, stream>>>(bsum, nb);
  k_scan3<<<nb, NTHREADS, 0, stream>>>(rp, bsum, n, e);
  k_scatter<<<ebl, NTHREADS, 0, stream>>>(row, col, rp, cur, dis, cols, vals, e);
  k_wprime<<<dim3(36, NLAYERS), NTHREADS, 0, stream>>>(cw, wp);
  k_lin0<<<r64, NTHREADS, 0, stream>>>(x, w0, b0, x0, n);

  const float* hin = x0;
  for (int l = 0; l < NLAYERS; ++l) {
    float* hout = (l & 1) ? hB : hA;
    k_spmm<<<(n + 7) / 8, NTHREADS, 0, stream>>>(hin, x0, hout, rp, cols, vals, sv, n);
    k_gemm<<<r64, NTHREADS, 0, stream>>>(hout, wp + (size_t)l * HID * HID, n);
    hin = hout;
  }
  k_lin1<<<r64, NTHREADS, 0, stream>>>(hin, w1, b1, (float*)d_out, n);
}

// Round 2
// 1358.716 us; speedup vs baseline: 1.0743x; 1.0743x over previous
//
#include <hip/hip_runtime.h>

#define NTHREADS 256
#define HID 96
#define INF 64
#define OUTF 16
#define NLAYERS 16

typedef __attribute__((ext_vector_type(8))) unsigned short ushort8_t;

static __device__ __forceinline__ float bf2f(unsigned short u) {
  return __uint_as_float(((unsigned)u) << 16);
}
static __device__ __forceinline__ unsigned short f2bf(float x) {
  unsigned u = __float_as_uint(x);
  return (unsigned short)((u + 0x7FFF + ((u >> 16) & 1)) >> 16);  // RNE
}
static __device__ __forceinline__ unsigned pack2bf(float a, float b) {
  return (unsigned)f2bf(a) | ((unsigned)f2bf(b) << 16);
}

// ---------------- preprocessing ----------------
__global__ void k_init(int* __restrict__ deg, int* __restrict__ cnt,
                       int* __restrict__ cur, int n) {
  int i = blockIdx.x * NTHREADS + threadIdx.x;
  if (i < n) { deg[i] = 1; cnt[i] = 0; cur[i] = 0; }  // deg=1 accounts for self-loop
}

__global__ void k_count(const int* __restrict__ row, const int* __restrict__ col,
                        int* __restrict__ deg, int* __restrict__ cnt, int e) {
  int i = blockIdx.x * NTHREADS + threadIdx.x;
  if (i < e) {
    atomicAdd(deg + col[i], 1);   // degree over col (+ self-loop via init)
    atomicAdd(cnt + row[i], 1);   // CSR row counts
  }
}

__global__ void k_dis(const int* __restrict__ deg, float* __restrict__ dis,
                      float* __restrict__ selfval, int n) {
  int i = blockIdx.x * NTHREADS + threadIdx.x;
  if (i < n) {
    float d = (float)deg[i];
    dis[i] = rsqrtf(d);
    selfval[i] = 1.0f / d;        // dis[i]^2 for the self-loop edge
  }
}

__global__ void k_scan1(const int* __restrict__ cnt, int* __restrict__ rp,
                        int* __restrict__ bsum, int n) {
  __shared__ int sh[NTHREADS];
  int t = threadIdx.x;
  int i = blockIdx.x * NTHREADS + t;
  int v = (i < n) ? cnt[i] : 0;
  sh[t] = v;
  __syncthreads();
  for (int ofs = 1; ofs < NTHREADS; ofs <<= 1) {
    int u = (t >= ofs) ? sh[t - ofs] : 0;
    __syncthreads();
    sh[t] += u;
    __syncthreads();
  }
  if (i < n) rp[i] = sh[t] - v;
  if (t == NTHREADS - 1) bsum[blockIdx.x] = sh[t];
}

__global__ void k_scan2(int* __restrict__ bsum, int nb) {  // nb <= 256
  __shared__ int sh[NTHREADS];
  int t = threadIdx.x;
  int v = (t < nb) ? bsum[t] : 0;
  sh[t] = v;
  __syncthreads();
  for (int ofs = 1; ofs < NTHREADS; ofs <<= 1) {
    int u = (t >= ofs) ? sh[t - ofs] : 0;
    __syncthreads();
    sh[t] += u;
    __syncthreads();
  }
  if (t < nb) bsum[t] = sh[t] - v;
}

__global__ void k_scan3(int* __restrict__ rp, const int* __restrict__ bsum,
                        int n, int etot) {
  int i = blockIdx.x * NTHREADS + threadIdx.x;
  if (i < n) rp[i] += bsum[blockIdx.x];
  if (i == 0) rp[n] = etot;
}

__global__ void k_scatter(const int* __restrict__ row, const int* __restrict__ col,
                          const int* __restrict__ rp, int* __restrict__ cur,
                          const float* __restrict__ dis, int2* __restrict__ ev,
                          int e) {
  int i = blockIdx.x * NTHREADS + threadIdx.x;
  if (i < e) {
    int r = row[i], c = col[i];
    int p = rp[r] + atomicAdd(cur + r, 1);
    int2 v;
    v.x = c;
    v.y = __float_as_int(dis[r] * dis[c]);
    ev[p] = v;
  }
}

// w'_l = (1-beta_l) I + beta_l * w_l
__global__ void k_wprime(const float* __restrict__ cw, float* __restrict__ wp) {
  int l = blockIdx.y;
  int idx = blockIdx.x * NTHREADS + threadIdx.x;   // 0..9215
  int k = idx / HID, f = idx % HID;
  float beta = logf(0.5f / (float)(l + 1) + 1.0f);
  float v = beta * cw[l * HID * HID + idx];
  if (k == f) v += 1.0f - beta;
  wp[l * HID * HID + idx] = v;
}

// ---------------- h0 = relu(x @ w0^T + b0) -> x0f (fp32) + hb0 (bf16) ----------
__global__ __launch_bounds__(NTHREADS) void k_lin0(
    const float* __restrict__ x, const float* __restrict__ w0,
    const float* __restrict__ b0, float* __restrict__ x0f,
    unsigned short* __restrict__ hb0, int n) {
  __shared__ float wl[INF * HID];   // wl[c][h], stride 96
  __shared__ float xT[INF * 68];    // xT[c][r], padded stride 68
  int tid = threadIdx.x;
#pragma unroll
  for (int i = 0; i < 6; ++i) {     // w0: 96x64 = 1536 float4
    int idx = tid + i * NTHREADS;
    int hrow = idx / 16, q = idx % 16;
    float4 v = *(const float4*)(w0 + hrow * INF + q * 4);
    wl[(q * 4 + 0) * HID + hrow] = v.x;
    wl[(q * 4 + 1) * HID + hrow] = v.y;
    wl[(q * 4 + 2) * HID + hrow] = v.z;
    wl[(q * 4 + 3) * HID + hrow] = v.w;
  }
  int r0 = blockIdx.x * 64;
#pragma unroll
  for (int i = 0; i < 4; ++i) {     // x tile: 64x64 = 1024 float4
    int idx = tid + i * NTHREADS;
    int r = idx / 16, q = idx % 16;
    int gr = r0 + r;
    float4 v = make_float4(0.f, 0.f, 0.f, 0.f);
    if (gr < n) v = *(const float4*)(x + (size_t)gr * INF + q * 4);
    xT[(q * 4 + 0) * 68 + r] = v.x;
    xT[(q * 4 + 1) * 68 + r] = v.y;
    xT[(q * 4 + 2) * 68 + r] = v.z;
    xT[(q * 4 + 3) * 68 + r] = v.w;
  }
  __syncthreads();
  int rg = tid & 15, cg = tid >> 4;
  float acc[4][6];
#pragma unroll
  for (int i = 0; i < 4; ++i)
#pragma unroll
    for (int j = 0; j < 6; ++j) acc[i][j] = 0.f;
#pragma unroll 4
  for (int k = 0; k < INF; ++k) {
    float4 s4 = *(const float4*)(xT + k * 68 + rg * 4);
    const float2* w2 = (const float2*)(wl + k * HID + cg * 6);
    float2 wa = w2[0], wb = w2[1], wc = w2[2];
    float wv[6] = {wa.x, wa.y, wb.x, wb.y, wc.x, wc.y};
    float sv[4] = {s4.x, s4.y, s4.z, s4.w};
#pragma unroll
    for (int i = 0; i < 4; ++i)
#pragma unroll
      for (int j = 0; j < 6; ++j) acc[i][j] = fmaf(sv[i], wv[j], acc[i][j]);
  }
  float bb[6];
#pragma unroll
  for (int j = 0; j < 6; ++j) bb[j] = b0[cg * 6 + j];
#pragma unroll
  for (int i = 0; i < 4; ++i) {
    int gr = r0 + rg * 4 + i;
    if (gr < n) {
      float r_[6];
#pragma unroll
      for (int j = 0; j < 6; ++j) r_[j] = fmaxf(acc[i][j] + bb[j], 0.f);
      float* o = x0f + (size_t)gr * HID + cg * 6;
#pragma unroll
      for (int j = 0; j < 6; ++j) o[j] = r_[j];
      unsigned* ob = (unsigned*)(hb0 + (size_t)gr * HID + cg * 6);
      ob[0] = pack2bf(r_[0], r_[1]);
      ob[1] = pack2bf(r_[2], r_[3]);
      ob[2] = pack2bf(r_[4], r_[5]);
    }
  }
}

// ------- SpMM + residual: s = 0.9*(A_hat h) + 0.1*x0 ; h gathered as bf16 -----
__global__ __launch_bounds__(NTHREADS) void k_spmm(
    const unsigned short* __restrict__ hin, const float* __restrict__ x0,
    float* __restrict__ sout, const int* __restrict__ rp,
    const int2* __restrict__ ev, const float* __restrict__ selfval, int n) {
  int sub = threadIdx.x & 31;
  int r = blockIdx.x * 8 + (threadIdx.x >> 5);
  if (r >= n) return;
  const unsigned short* hr = hin + (size_t)r * HID;
  float svv = selfval[r];
  float a0 = svv * bf2f(hr[sub]);
  float a1 = svv * bf2f(hr[sub + 32]);
  float a2 = svv * bf2f(hr[sub + 64]);
  int e0 = rp[r], e1 = rp[r + 1];
  for (int ei = e0; ei < e1; ++ei) {
    int2 cv = ev[ei];
    int c = cv.x;
    float v = __int_as_float(cv.y);
    const unsigned short* hc = hin + (size_t)c * HID;
    a0 = fmaf(v, bf2f(hc[sub]), a0);
    a1 = fmaf(v, bf2f(hc[sub + 32]), a1);
    a2 = fmaf(v, bf2f(hc[sub + 64]), a2);
  }
  size_t o = (size_t)r * HID;
  sout[o + sub]      = 0.9f * a0 + 0.1f * x0[o + sub];
  sout[o + sub + 32] = 0.9f * a1 + 0.1f * x0[o + sub + 32];
  sout[o + sub + 64] = 0.9f * a2 + 0.1f * x0[o + sub + 64];
}

// ---------- h' = relu(s @ w'), s fp32 in, h' bf16 out, 64 rows/block ----------
__global__ __launch_bounds__(NTHREADS) void k_gemm(
    const float* __restrict__ s, const float* __restrict__ wp,
    unsigned short* __restrict__ hout, int n) {
  __shared__ float wl[HID * HID];   // [k][f]
  __shared__ float sT[HID * 68];    // [k][r], padded stride 68
  int tid = threadIdx.x;
  {
    const float4* wp4 = (const float4*)wp;
    float4* wl4 = (float4*)wl;
#pragma unroll
    for (int i = 0; i < 9; ++i) wl4[tid + i * NTHREADS] = wp4[tid + i * NTHREADS];
  }
  int r0 = blockIdx.x * 64;
#pragma unroll
  for (int i = 0; i < 6; ++i) {     // s tile: 64x96 = 1536 float4
    int idx = tid + i * NTHREADS;
    int r = idx / 24, q = idx % 24;
    int gr = r0 + r;
    float4 v = make_float4(0.f, 0.f, 0.f, 0.f);
    if (gr < n) v = *(const float4*)(s + (size_t)gr * HID + q * 4);
    sT[(q * 4 + 0) * 68 + r] = v.x;
    sT[(q * 4 + 1) * 68 + r] = v.y;
    sT[(q * 4 + 2) * 68 + r] = v.z;
    sT[(q * 4 + 3) * 68 + r] = v.w;
  }
  __syncthreads();
  int rg = tid & 15, cg = tid >> 4;
  float acc[4][6];
#pragma unroll
  for (int i = 0; i < 4; ++i)
#pragma unroll
    for (int j = 0; j < 6; ++j) acc[i][j] = 0.f;
#pragma unroll 4
  for (int k = 0; k < HID; ++k) {
    float4 s4 = *(const float4*)(sT + k * 68 + rg * 4);
    const float2* w2 = (const float2*)(wl + k * HID + cg * 6);
    float2 wa = w2[0], wb = w2[1], wc = w2[2];
    float wv[6] = {wa.x, wa.y, wb.x, wb.y, wc.x, wc.y};
    float sv4[4] = {s4.x, s4.y, s4.z, s4.w};
#pragma unroll
    for (int i = 0; i < 4; ++i)
#pragma unroll
      for (int j = 0; j < 6; ++j) acc[i][j] = fmaf(sv4[i], wv[j], acc[i][j]);
  }
#pragma unroll
  for (int i = 0; i < 4; ++i) {
    int gr = r0 + rg * 4 + i;
    if (gr < n) {
      unsigned* o = (unsigned*)(hout + (size_t)gr * HID + cg * 6);
      o[0] = pack2bf(fmaxf(acc[i][0], 0.f), fmaxf(acc[i][1], 0.f));
      o[1] = pack2bf(fmaxf(acc[i][2], 0.f), fmaxf(acc[i][3], 0.f));
      o[2] = pack2bf(fmaxf(acc[i][4], 0.f), fmaxf(acc[i][5], 0.f));
    }
  }
}

// ---------------- out = h @ w1^T + b1  (h is bf16) ----------------
__global__ __launch_bounds__(NTHREADS) void k_lin1(
    const unsigned short* __restrict__ h, const float* __restrict__ w1,
    const float* __restrict__ b1, float* __restrict__ out, int n) {
  __shared__ float hT[HID * 68];    // [k][r]
  __shared__ float w1l[HID * OUTF]; // [k][o]
  int tid = threadIdx.x;
#pragma unroll
  for (int i = 0; i < 6; ++i) {     // w1: 16x96 = 1536 floats
    int idx = tid + i * NTHREADS;
    int o = idx / HID, k = idx % HID;
    w1l[k * OUTF + o] = w1[idx];
  }
  int r0 = blockIdx.x * 64;
#pragma unroll
  for (int i = 0; i < 3; ++i) {     // h tile: 64x96 bf16 = 768 ushort8
    int idx = tid + i * NTHREADS;
    int r = idx / 12, q = idx % 12;
    int gr = r0 + r;
    ushort8_t v = (ushort8_t)0;
    if (gr < n) v = *(const ushort8_t*)(h + (size_t)gr * HID + q * 8);
#pragma unroll
    for (int j = 0; j < 8; ++j) hT[(q * 8 + j) * 68 + r] = bf2f(v[j]);
  }
  __syncthreads();
  int r = tid & 63, og = tid >> 6;
  float acc[4] = {0.f, 0.f, 0.f, 0.f};
#pragma unroll 4
  for (int k = 0; k < HID; ++k) {
    float s = hT[k * 68 + r];
    float4 w4 = *(const float4*)(w1l + k * OUTF + og * 4);
    acc[0] = fmaf(s, w4.x, acc[0]);
    acc[1] = fmaf(s, w4.y, acc[1]);
    acc[2] = fmaf(s, w4.z, acc[2]);
    acc[3] = fmaf(s, w4.w, acc[3]);
  }
  int gr = r0 + r;
  if (gr < n) {
    float* op = out + (size_t)gr * OUTF + og * 4;
#pragma unroll
    for (int j = 0; j < 4; ++j) op[j] = acc[j] + b1[og * 4 + j];
  }
}

extern "C" void kernel_launch(void* const* d_in, const int* in_sizes, int n_in,
                              void* d_out, int out_size, void* d_ws, size_t ws_size,
                              hipStream_t stream) {
  const float* x  = (const float*)d_in[0];
  const int*   ei = (const int*)d_in[1];     // [2][E]: rows then cols
  const float* w0 = (const float*)d_in[2];
  const float* b0 = (const float*)d_in[3];
  const float* w1 = (const float*)d_in[4];
  const float* b1 = (const float*)d_in[5];
  const float* cw = (const float*)d_in[6];
  int n = in_sizes[0] / INF;    // 50000
  int e = in_sizes[1] / 2;      // 800000
  const int* row = ei;
  const int* col = ei + e;

  char* ws = (char*)d_ws;
  size_t off = 0;
  auto alloc = [&](size_t bytes) -> void* {
    void* p = (void*)(ws + off);
    off += (bytes + 255) & ~(size_t)255;
    return p;
  };
  float*          x0f = (float*)alloc((size_t)n * HID * 4);
  float*          sbuf= (float*)alloc((size_t)n * HID * 4);
  unsigned short* hbA = (unsigned short*)alloc((size_t)n * HID * 2);
  unsigned short* hbB = (unsigned short*)alloc((size_t)n * HID * 2);
  float* wp   = (float*)alloc((size_t)NLAYERS * HID * HID * 4);
  int*   deg  = (int*)alloc((size_t)n * 4);
  float* dis  = (float*)alloc((size_t)n * 4);
  float* sv   = (float*)alloc((size_t)n * 4);
  int*   cnt  = (int*)alloc((size_t)n * 4);
  int*   cur  = (int*)alloc((size_t)n * 4);
  int*   rp   = (int*)alloc((size_t)(n + 1) * 4);
  int2*  ev   = (int2*)alloc((size_t)e * 8);
  int*   bsum = (int*)alloc(1024 * 4);
  (void)ws_size; (void)n_in; (void)out_size;

  int nb  = (n + NTHREADS - 1) / NTHREADS;   // 196
  int ebl = (e + NTHREADS - 1) / NTHREADS;   // 3125
  int r64 = (n + 63) / 64;                   // 782

  k_init<<<nb, NTHREADS, 0, stream>>>(deg, cnt, cur, n);
  k_count<<<ebl, NTHREADS, 0, stream>>>(row, col, deg, cnt, e);
  k_dis<<<nb, NTHREADS, 0, stream>>>(deg, dis, sv, n);
  k_scan1<<<nb, NTHREADS, 0, stream>>>(cnt, rp, bsum, n);
  k_scan2<<<1, NTHREADS, 0, stream>>>(bsum, nb);
  k_scan3<<<nb, NTHREADS, 0, stream>>>(rp, bsum, n, e);
  k_scatter<<<ebl, NTHREADS, 0, stream>>>(row, col, rp, cur, dis, ev, e);
  k_wprime<<<dim3(36, NLAYERS), NTHREADS, 0, stream>>>(cw, wp);
  k_lin0<<<r64, NTHREADS, 0, stream>>>(x, w0, b0, x0f, hbA, n);

  const unsigned short* hin = hbA;
  for (int l = 0; l < NLAYERS; ++l) {
    unsigned short* hout = (l & 1) ? hbA : hbB;
    k_spmm<<<(n + 7) / 8, NTHREADS, 0, stream>>>(hin, x0f, sbuf, rp, ev, sv, n);
    k_gemm<<<r64, NTHREADS, 0, stream>>>(sbuf, wp + (size_t)l * HID * HID, hout, n);
    hin = hout;
  }
  k_lin1<<<r64, NTHREADS, 0, stream>>>(hin, w1, b1, (float*)d_out, n);
}

// Round 3
// 953.157 us; speedup vs baseline: 1.5313x; 1.4255x over previous
//
#include <hip/hip_runtime.h>

#define NTHREADS 256
#define HID 96
#define INF 64
#define OUTF 16
#define NLAYERS 16

typedef __attribute__((ext_vector_type(8))) unsigned short ushort8_t;

static __device__ __forceinline__ float bf2f(unsigned short u) {
  return __uint_as_float(((unsigned)u) << 16);
}
static __device__ __forceinline__ unsigned short f2bf(float x) {
  unsigned u = __float_as_uint(x);
  return (unsigned short)((u + 0x7FFF + ((u >> 16) & 1)) >> 16);  // RNE
}
static __device__ __forceinline__ unsigned pack2bf(float a, float b) {
  return (unsigned)f2bf(a) | ((unsigned)f2bf(b) << 16);
}

// ---------------- preprocessing ----------------
__global__ void k_init(int* __restrict__ deg, int* __restrict__ cnt,
                       int* __restrict__ cur, int n) {
  int i = blockIdx.x * NTHREADS + threadIdx.x;
  // deg=1: self-loop contributes to degree. cnt=1/cur=1: slot 0 of each CSR row
  // is reserved for the self-loop edge (filled by k_self).
  if (i < n) { deg[i] = 1; cnt[i] = 1; cur[i] = 1; }
}

__global__ void k_count(const int* __restrict__ row, const int* __restrict__ col,
                        int* __restrict__ deg, int* __restrict__ cnt, int e) {
  int i = blockIdx.x * NTHREADS + threadIdx.x;
  if (i < e) {
    atomicAdd(deg + col[i], 1);   // degree over col (+ self-loop via init)
    atomicAdd(cnt + row[i], 1);   // CSR row counts (incl. reserved self slot)
  }
}

__global__ void k_dis(const int* __restrict__ deg, float* __restrict__ dis,
                      float* __restrict__ selfval, int n) {
  int i = blockIdx.x * NTHREADS + threadIdx.x;
  if (i < n) {
    float d = (float)deg[i];
    dis[i] = rsqrtf(d);
    selfval[i] = 1.0f / d;        // dis[i]^2 for the self-loop edge
  }
}

__global__ void k_scan1(const int* __restrict__ cnt, int* __restrict__ rp,
                        int* __restrict__ bsum, int n) {
  __shared__ int sh[NTHREADS];
  int t = threadIdx.x;
  int i = blockIdx.x * NTHREADS + t;
  int v = (i < n) ? cnt[i] : 0;
  sh[t] = v;
  __syncthreads();
  for (int ofs = 1; ofs < NTHREADS; ofs <<= 1) {
    int u = (t >= ofs) ? sh[t - ofs] : 0;
    __syncthreads();
    sh[t] += u;
    __syncthreads();
  }
  if (i < n) rp[i] = sh[t] - v;
  if (t == NTHREADS - 1) bsum[blockIdx.x] = sh[t];
}

__global__ void k_scan2(int* __restrict__ bsum, int nb) {  // nb <= 256
  __shared__ int sh[NTHREADS];
  int t = threadIdx.x;
  int v = (t < nb) ? bsum[t] : 0;
  sh[t] = v;
  __syncthreads();
  for (int ofs = 1; ofs < NTHREADS; ofs <<= 1) {
    int u = (t >= ofs) ? sh[t - ofs] : 0;
    __syncthreads();
    sh[t] += u;
    __syncthreads();
  }
  if (t < nb) bsum[t] = sh[t] - v;
}

__global__ void k_scan3(int* __restrict__ rp, const int* __restrict__ bsum,
                        int n, int etot) {
  int i = blockIdx.x * NTHREADS + threadIdx.x;
  if (i < n) rp[i] += bsum[blockIdx.x];
  if (i == 0) rp[n] = etot;
}

// fill reserved slot 0 of each row with the self-loop edge
__global__ void k_self(const int* __restrict__ rp, const float* __restrict__ sv,
                       int2* __restrict__ ev, int n) {
  int i = blockIdx.x * NTHREADS + threadIdx.x;
  if (i < n) {
    int2 v;
    v.x = i;
    v.y = __float_as_int(sv[i]);
    ev[rp[i]] = v;
  }
}

__global__ void k_scatter(const int* __restrict__ row, const int* __restrict__ col,
                          const int* __restrict__ rp, int* __restrict__ cur,
                          const float* __restrict__ dis, int2* __restrict__ ev,
                          int e) {
  int i = blockIdx.x * NTHREADS + threadIdx.x;
  if (i < e) {
    int r = row[i], c = col[i];
    int p = rp[r] + atomicAdd(cur + r, 1);
    int2 v;
    v.x = c;
    v.y = __float_as_int(dis[r] * dis[c]);
    ev[p] = v;
  }
}

// w'_l = (1-beta_l) I + beta_l * w_l
__global__ void k_wprime(const float* __restrict__ cw, float* __restrict__ wp) {
  int l = blockIdx.y;
  int idx = blockIdx.x * NTHREADS + threadIdx.x;   // 0..9215
  int k = idx / HID, f = idx % HID;
  float beta = logf(0.5f / (float)(l + 1) + 1.0f);
  float v = beta * cw[l * HID * HID + idx];
  if (k == f) v += 1.0f - beta;
  wp[l * HID * HID + idx] = v;
}

// ---------------- h0 = relu(x @ w0^T + b0) -> x0f (fp32) + hb0 (bf16) ----------
__global__ __launch_bounds__(NTHREADS) void k_lin0(
    const float* __restrict__ x, const float* __restrict__ w0,
    const float* __restrict__ b0, float* __restrict__ x0f,
    unsigned short* __restrict__ hb0, int n) {
  __shared__ float wl[INF * HID];   // wl[c][h], stride 96
  __shared__ float xT[INF * 68];    // xT[c][r], padded stride 68
  int tid = threadIdx.x;
#pragma unroll
  for (int i = 0; i < 6; ++i) {     // w0: 96x64 = 1536 float4
    int idx = tid + i * NTHREADS;
    int hrow = idx / 16, q = idx % 16;
    float4 v = *(const float4*)(w0 + hrow * INF + q * 4);
    wl[(q * 4 + 0) * HID + hrow] = v.x;
    wl[(q * 4 + 1) * HID + hrow] = v.y;
    wl[(q * 4 + 2) * HID + hrow] = v.z;
    wl[(q * 4 + 3) * HID + hrow] = v.w;
  }
  int r0 = blockIdx.x * 64;
#pragma unroll
  for (int i = 0; i < 4; ++i) {     // x tile: 64x64 = 1024 float4
    int idx = tid + i * NTHREADS;
    int r = idx / 16, q = idx % 16;
    int gr = r0 + r;
    float4 v = make_float4(0.f, 0.f, 0.f, 0.f);
    if (gr < n) v = *(const float4*)(x + (size_t)gr * INF + q * 4);
    xT[(q * 4 + 0) * 68 + r] = v.x;
    xT[(q * 4 + 1) * 68 + r] = v.y;
    xT[(q * 4 + 2) * 68 + r] = v.z;
    xT[(q * 4 + 3) * 68 + r] = v.w;
  }
  __syncthreads();
  int rg = tid & 15, cg = tid >> 4;
  float acc[4][6];
#pragma unroll
  for (int i = 0; i < 4; ++i)
#pragma unroll
    for (int j = 0; j < 6; ++j) acc[i][j] = 0.f;
#pragma unroll 4
  for (int k = 0; k < INF; ++k) {
    float4 s4 = *(const float4*)(xT + k * 68 + rg * 4);
    const float2* w2 = (const float2*)(wl + k * HID + cg * 6);
    float2 wa = w2[0], wb = w2[1], wc = w2[2];
    float wv[6] = {wa.x, wa.y, wb.x, wb.y, wc.x, wc.y};
    float sv[4] = {s4.x, s4.y, s4.z, s4.w};
#pragma unroll
    for (int i = 0; i < 4; ++i)
#pragma unroll
      for (int j = 0; j < 6; ++j) acc[i][j] = fmaf(sv[i], wv[j], acc[i][j]);
  }
  float bb[6];
#pragma unroll
  for (int j = 0; j < 6; ++j) bb[j] = b0[cg * 6 + j];
#pragma unroll
  for (int i = 0; i < 4; ++i) {
    int gr = r0 + rg * 4 + i;
    if (gr < n) {
      float r_[6];
#pragma unroll
      for (int j = 0; j < 6; ++j) r_[j] = fmaxf(acc[i][j] + bb[j], 0.f);
      float* o = x0f + (size_t)gr * HID + cg * 6;
#pragma unroll
      for (int j = 0; j < 6; ++j) o[j] = r_[j];
      unsigned* ob = (unsigned*)(hb0 + (size_t)gr * HID + cg * 6);
      ob[0] = pack2bf(r_[0], r_[1]);
      ob[1] = pack2bf(r_[2], r_[3]);
      ob[2] = pack2bf(r_[4], r_[5]);
    }
  }
}

// ------- SpMM + residual: s = 0.9*(A_hat h) + 0.1*x0 ------------------------
// half-wave per row; 32 lanes = 8 edge-slots x 4 feature-groups (24 feats each).
// Self-loop is a regular CSR edge (slot 0). LDS transpose-reduce across edge
// slots, stride padded to 100 floats (all 8 bank groups hit evenly).
__global__ __launch_bounds__(NTHREADS) void k_spmm(
    const unsigned short* __restrict__ hin, const float* __restrict__ x0,
    float* __restrict__ sout, const int* __restrict__ rp,
    const int2* __restrict__ ev, int n) {
  __shared__ float red[8][8][100];
  int t = threadIdx.x;
  int hw = t >> 5;            // half-wave id 0..7 (one row each)
  int lane = t & 31;
  int eb = lane >> 2;         // edge slot 0..7
  int fg = lane & 3;          // feature group 0..3 (24 features)
  int r = blockIdx.x * 8 + hw;
  if (r >= n) r = n - 1;      // clamp: duplicate work, benign same-value write
  int e0 = rp[r], e1 = rp[r + 1];   // >= 1 edge always (self-loop)
  float acc[24];
#pragma unroll
  for (int j = 0; j < 24; ++j) acc[j] = 0.f;

  int idx0 = e0 + eb;
  bool ok = idx0 < e1;
  idx0 = ok ? idx0 : e1 - 1;
  int2 cv = ev[idx0];
  for (int base = e0; base < e1; base += 8) {
    int2 cur = cv;
    bool okc = ok;
    int nb = base + 8;
    if (nb < e1) {            // prefetch next batch of edges
      int i2 = nb + eb;
      ok = i2 < e1;
      i2 = ok ? i2 : e1 - 1;
      cv = ev[i2];
    }
    float v = okc ? __int_as_float(cur.y) : 0.f;
    const unsigned short* hc = hin + (size_t)cur.x * HID + fg * 24;
    ushort8_t p0 = *(const ushort8_t*)(hc);
    ushort8_t p1 = *(const ushort8_t*)(hc + 8);
    ushort8_t p2 = *(const ushort8_t*)(hc + 16);
#pragma unroll
    for (int j = 0; j < 8; ++j) acc[j]      = fmaf(v, bf2f(p0[j]), acc[j]);
#pragma unroll
    for (int j = 0; j < 8; ++j) acc[8 + j]  = fmaf(v, bf2f(p1[j]), acc[8 + j]);
#pragma unroll
    for (int j = 0; j < 8; ++j) acc[16 + j] = fmaf(v, bf2f(p2[j]), acc[16 + j]);
  }
  // partial sums -> LDS
  float* myr = &red[hw][eb][fg * 24];
#pragma unroll
  for (int j = 0; j < 6; ++j)
    *(float4*)(myr + j * 4) =
        make_float4(acc[j * 4], acc[j * 4 + 1], acc[j * 4 + 2], acc[j * 4 + 3]);
  __syncthreads();
  // lanes 0..23 of each half-wave: sum 8 edge-slot copies of 4 features each
  if (lane < 24) {
    float4 tot = *(const float4*)(&red[hw][0][lane * 4]);
#pragma unroll
    for (int b = 1; b < 8; ++b) {
      float4 p = *(const float4*)(&red[hw][b][lane * 4]);
      tot.x += p.x; tot.y += p.y; tot.z += p.z; tot.w += p.w;
    }
    size_t o = (size_t)r * HID + lane * 4;
    float4 xr = *(const float4*)(x0 + o);
    float4 s4;
    s4.x = 0.9f * tot.x + 0.1f * xr.x;
    s4.y = 0.9f * tot.y + 0.1f * xr.y;
    s4.z = 0.9f * tot.z + 0.1f * xr.z;
    s4.w = 0.9f * tot.w + 0.1f * xr.w;
    *(float4*)(sout + o) = s4;
  }
}

// ---------- h' = relu(s @ w'), s fp32 in, h' bf16 out, 64 rows/block ----------
__global__ __launch_bounds__(NTHREADS) void k_gemm(
    const float* __restrict__ s, const float* __restrict__ wp,
    unsigned short* __restrict__ hout, int n) {
  __shared__ float wl[HID * HID];   // [k][f]
  __shared__ float sT[HID * 68];    // [k][r], padded stride 68
  int tid = threadIdx.x;
  {
    const float4* wp4 = (const float4*)wp;
    float4* wl4 = (float4*)wl;
#pragma unroll
    for (int i = 0; i < 9; ++i) wl4[tid + i * NTHREADS] = wp4[tid + i * NTHREADS];
  }
  int r0 = blockIdx.x * 64;
#pragma unroll
  for (int i = 0; i < 6; ++i) {     // s tile: 64x96 = 1536 float4
    int idx = tid + i * NTHREADS;
    int r = idx / 24, q = idx % 24;
    int gr = r0 + r;
    float4 v = make_float4(0.f, 0.f, 0.f, 0.f);
    if (gr < n) v = *(const float4*)(s + (size_t)gr * HID + q * 4);
    sT[(q * 4 + 0) * 68 + r] = v.x;
    sT[(q * 4 + 1) * 68 + r] = v.y;
    sT[(q * 4 + 2) * 68 + r] = v.z;
    sT[(q * 4 + 3) * 68 + r] = v.w;
  }
  __syncthreads();
  int rg = tid & 15, cg = tid >> 4;
  float acc[4][6];
#pragma unroll
  for (int i = 0; i < 4; ++i)
#pragma unroll
    for (int j = 0; j < 6; ++j) acc[i][j] = 0.f;
#pragma unroll 4
  for (int k = 0; k < HID; ++k) {
    float4 s4 = *(const float4*)(sT + k * 68 + rg * 4);
    const float2* w2 = (const float2*)(wl + k * HID + cg * 6);
    float2 wa = w2[0], wb = w2[1], wc = w2[2];
    float wv[6] = {wa.x, wa.y, wb.x, wb.y, wc.x, wc.y};
    float sv4[4] = {s4.x, s4.y, s4.z, s4.w};
#pragma unroll
    for (int i = 0; i < 4; ++i)
#pragma unroll
      for (int j = 0; j < 6; ++j) acc[i][j] = fmaf(sv4[i], wv[j], acc[i][j]);
  }
#pragma unroll
  for (int i = 0; i < 4; ++i) {
    int gr = r0 + rg * 4 + i;
    if (gr < n) {
      unsigned* o = (unsigned*)(hout + (size_t)gr * HID + cg * 6);
      o[0] = pack2bf(fmaxf(acc[i][0], 0.f), fmaxf(acc[i][1], 0.f));
      o[1] = pack2bf(fmaxf(acc[i][2], 0.f), fmaxf(acc[i][3], 0.f));
      o[2] = pack2bf(fmaxf(acc[i][4], 0.f), fmaxf(acc[i][5], 0.f));
    }
  }
}

// ---------------- out = h @ w1^T + b1  (h is bf16) ----------------
__global__ __launch_bounds__(NTHREADS) void k_lin1(
    const unsigned short* __restrict__ h, const float* __restrict__ w1,
    const float* __restrict__ b1, float* __restrict__ out, int n) {
  __shared__ float hT[HID * 68];    // [k][r]
  __shared__ float w1l[HID * OUTF]; // [k][o]
  int tid = threadIdx.x;
#pragma unroll
  for (int i = 0; i < 6; ++i) {     // w1: 16x96 = 1536 floats
    int idx = tid + i * NTHREADS;
    int o = idx / HID, k = idx % HID;
    w1l[k * OUTF + o] = w1[idx];
  }
  int r0 = blockIdx.x * 64;
#pragma unroll
  for (int i = 0; i < 3; ++i) {     // h tile: 64x96 bf16 = 768 ushort8
    int idx = tid + i * NTHREADS;
    int r = idx / 12, q = idx % 12;
    int gr = r0 + r;
    ushort8_t v = (ushort8_t)0;
    if (gr < n) v = *(const ushort8_t*)(h + (size_t)gr * HID + q * 8);
#pragma unroll
    for (int j = 0; j < 8; ++j) hT[(q * 8 + j) * 68 + r] = bf2f(v[j]);
  }
  __syncthreads();
  int r = tid & 63, og = tid >> 6;
  float acc[4] = {0.f, 0.f, 0.f, 0.f};
#pragma unroll 4
  for (int k = 0; k < HID; ++k) {
    float s = hT[k * 68 + r];
    float4 w4 = *(const float4*)(w1l + k * OUTF + og * 4);
    acc[0] = fmaf(s, w4.x, acc[0]);
    acc[1] = fmaf(s, w4.y, acc[1]);
    acc[2] = fmaf(s, w4.z, acc[2]);
    acc[3] = fmaf(s, w4.w, acc[3]);
  }
  int gr = r0 + r;
  if (gr < n) {
    float* op = out + (size_t)gr * OUTF + og * 4;
#pragma unroll
    for (int j = 0; j < 4; ++j) op[j] = acc[j] + b1[og * 4 + j];
  }
}

extern "C" void kernel_launch(void* const* d_in, const int* in_sizes, int n_in,
                              void* d_out, int out_size, void* d_ws, size_t ws_size,
                              hipStream_t stream) {
  const float* x  = (const float*)d_in[0];
  const int*   ei = (const int*)d_in[1];     // [2][E]: rows then cols
  const float* w0 = (const float*)d_in[2];
  const float* b0 = (const float*)d_in[3];
  const float* w1 = (const float*)d_in[4];
  const float* b1 = (const float*)d_in[5];
  const float* cw = (const float*)d_in[6];
  int n = in_sizes[0] / INF;    // 50000
  int e = in_sizes[1] / 2;      // 800000
  const int* row = ei;
  const int* col = ei + e;

  char* ws = (char*)d_ws;
  size_t off = 0;
  auto alloc = [&](size_t bytes) -> void* {
    void* p = (void*)(ws + off);
    off += (bytes + 255) & ~(size_t)255;
    return p;
  };
  float*          x0f = (float*)alloc((size_t)n * HID * 4);
  float*          sbuf= (float*)alloc((size_t)n * HID * 4);
  unsigned short* hbA = (unsigned short*)alloc((size_t)n * HID * 2);
  unsigned short* hbB = (unsigned short*)alloc((size_t)n * HID * 2);
  float* wp   = (float*)alloc((size_t)NLAYERS * HID * HID * 4);
  int*   deg  = (int*)alloc((size_t)n * 4);
  float* dis  = (float*)alloc((size_t)n * 4);
  float* sv   = (float*)alloc((size_t)n * 4);
  int*   cnt  = (int*)alloc((size_t)n * 4);
  int*   cur  = (int*)alloc((size_t)n * 4);
  int*   rp   = (int*)alloc((size_t)(n + 1) * 4);
  int2*  ev   = (int2*)alloc((size_t)(e + n) * 8);  // + self-loop slots
  int*   bsum = (int*)alloc(1024 * 4);
  (void)ws_size; (void)n_in; (void)out_size;

  int nb  = (n + NTHREADS - 1) / NTHREADS;   // 196
  int ebl = (e + NTHREADS - 1) / NTHREADS;   // 3125
  int r64 = (n + 63) / 64;                   // 782

  k_init<<<nb, NTHREADS, 0, stream>>>(deg, cnt, cur, n);
  k_count<<<ebl, NTHREADS, 0, stream>>>(row, col, deg, cnt, e);
  k_dis<<<nb, NTHREADS, 0, stream>>>(deg, dis, sv, n);
  k_scan1<<<nb, NTHREADS, 0, stream>>>(cnt, rp, bsum, n);
  k_scan2<<<1, NTHREADS, 0, stream>>>(bsum, nb);
  k_scan3<<<nb, NTHREADS, 0, stream>>>(rp, bsum, n, e + n);
  k_self<<<nb, NTHREADS, 0, stream>>>(rp, sv, ev, n);
  k_scatter<<<ebl, NTHREADS, 0, stream>>>(row, col, rp, cur, dis, ev, e);
  k_wprime<<<dim3(36, NLAYERS), NTHREADS, 0, stream>>>(cw, wp);
  k_lin0<<<r64, NTHREADS, 0, stream>>>(x, w0, b0, x0f, hbA, n);

  const unsigned short* hin = hbA;
  for (int l = 0; l < NLAYERS; ++l) {
    unsigned short* hout = (l & 1) ? hbA : hbB;
    k_spmm<<<(n + 7) / 8, NTHREADS, 0, stream>>>(hin, x0f, sbuf, rp, ev, n);
    k_gemm<<<r64, NTHREADS, 0, stream>>>(sbuf, wp + (size_t)l * HID * HID, hout, n);
    hin = hout;
  }
  k_lin1<<<r64, NTHREADS, 0, stream>>>(hin, w1, b1, (float*)d_out, n);
}

// Round 4
// 793.557 us; speedup vs baseline: 1.8393x; 1.2011x over previous
//
#include <hip/hip_runtime.h>

#define NTHREADS 256
#define HID 96
#define INF 64
#define OUTF 16
#define NLAYERS 16

typedef __attribute__((ext_vector_type(8))) unsigned short ushort8_t;
typedef __attribute__((ext_vector_type(8))) short short8_t;   // MFMA bf16 A/B frag
typedef __attribute__((ext_vector_type(4))) float f32x4_t;    // MFMA C/D frag

static __device__ __forceinline__ float bf2f(unsigned short u) {
  return __uint_as_float(((unsigned)u) << 16);
}
static __device__ __forceinline__ unsigned short f2bf(float x) {
  unsigned u = __float_as_uint(x);
  return (unsigned short)((u + 0x7FFF + ((u >> 16) & 1)) >> 16);  // RNE
}
static __device__ __forceinline__ unsigned pack2bf(float a, float b) {
  return (unsigned)f2bf(a) | ((unsigned)f2bf(b) << 16);
}

// ---------------- preprocessing ----------------
__global__ void k_init(int* __restrict__ deg, int* __restrict__ cnt,
                       int* __restrict__ cur, int n) {
  int i = blockIdx.x * NTHREADS + threadIdx.x;
  // deg=1: self-loop contributes to degree. cnt=1/cur=1: slot 0 of each CSR row
  // is reserved for the self-loop edge (filled by k_self).
  if (i < n) { deg[i] = 1; cnt[i] = 1; cur[i] = 1; }
}

__global__ void k_count(const int* __restrict__ row, const int* __restrict__ col,
                        int* __restrict__ deg, int* __restrict__ cnt, int e) {
  int i = blockIdx.x * NTHREADS + threadIdx.x;
  if (i < e) {
    atomicAdd(deg + col[i], 1);   // degree over col (+ self-loop via init)
    atomicAdd(cnt + row[i], 1);   // CSR row counts (incl. reserved self slot)
  }
}

__global__ void k_dis(const int* __restrict__ deg, float* __restrict__ dis,
                      float* __restrict__ selfval, int n) {
  int i = blockIdx.x * NTHREADS + threadIdx.x;
  if (i < n) {
    float d = (float)deg[i];
    dis[i] = rsqrtf(d);
    selfval[i] = 1.0f / d;        // dis[i]^2 for the self-loop edge
  }
}

__global__ void k_scan1(const int* __restrict__ cnt, int* __restrict__ rp,
                        int* __restrict__ bsum, int n) {
  __shared__ int sh[NTHREADS];
  int t = threadIdx.x;
  int i = blockIdx.x * NTHREADS + t;
  int v = (i < n) ? cnt[i] : 0;
  sh[t] = v;
  __syncthreads();
  for (int ofs = 1; ofs < NTHREADS; ofs <<= 1) {
    int u = (t >= ofs) ? sh[t - ofs] : 0;
    __syncthreads();
    sh[t] += u;
    __syncthreads();
  }
  if (i < n) rp[i] = sh[t] - v;
  if (t == NTHREADS - 1) bsum[blockIdx.x] = sh[t];
}

__global__ void k_scan2(int* __restrict__ bsum, int nb) {  // nb <= 256
  __shared__ int sh[NTHREADS];
  int t = threadIdx.x;
  int v = (t < nb) ? bsum[t] : 0;
  sh[t] = v;
  __syncthreads();
  for (int ofs = 1; ofs < NTHREADS; ofs <<= 1) {
    int u = (t >= ofs) ? sh[t - ofs] : 0;
    __syncthreads();
    sh[t] += u;
    __syncthreads();
  }
  if (t < nb) bsum[t] = sh[t] - v;
}

__global__ void k_scan3(int* __restrict__ rp, const int* __restrict__ bsum,
                        int n, int etot) {
  int i = blockIdx.x * NTHREADS + threadIdx.x;
  if (i < n) rp[i] += bsum[blockIdx.x];
  if (i == 0) rp[n] = etot;
}

// fill reserved slot 0 of each row with the self-loop edge
__global__ void k_self(const int* __restrict__ rp, const float* __restrict__ sv,
                       int2* __restrict__ ev, int n) {
  int i = blockIdx.x * NTHREADS + threadIdx.x;
  if (i < n) {
    int2 v;
    v.x = i;
    v.y = __float_as_int(sv[i]);
    ev[rp[i]] = v;
  }
}

__global__ void k_scatter(const int* __restrict__ row, const int* __restrict__ col,
                          const int* __restrict__ rp, int* __restrict__ cur,
                          const float* __restrict__ dis, int2* __restrict__ ev,
                          int e) {
  int i = blockIdx.x * NTHREADS + threadIdx.x;
  if (i < e) {
    int r = row[i], c = col[i];
    int p = rp[r] + atomicAdd(cur + r, 1);
    int2 v;
    v.x = c;
    v.y = __float_as_int(dis[r] * dis[c]);
    ev[p] = v;
  }
}

// wT_bf16[l][f][k] = bf16(conv_w[l][k][f])  (transposed for MFMA B-fragments)
__global__ void k_wprime(const float* __restrict__ cw,
                         unsigned short* __restrict__ wTb) {
  int l = blockIdx.y;
  int idx = blockIdx.x * NTHREADS + threadIdx.x;   // 0..9215 = f*96 + k
  int f = idx / HID, k = idx % HID;
  wTb[l * HID * HID + idx] = f2bf(cw[l * HID * HID + k * HID + f]);
}

// ---------------- h0 = relu(x @ w0^T + b0) -> x0f (fp32) + hb0 (bf16) ----------
__global__ __launch_bounds__(NTHREADS) void k_lin0(
    const float* __restrict__ x, const float* __restrict__ w0,
    const float* __restrict__ b0, float* __restrict__ x0f,
    unsigned short* __restrict__ hb0, int n) {
  __shared__ float wl[INF * HID];   // wl[c][h], stride 96
  __shared__ float xT[INF * 68];    // xT[c][r], padded stride 68
  int tid = threadIdx.x;
#pragma unroll
  for (int i = 0; i < 6; ++i) {     // w0: 96x64 = 1536 float4
    int idx = tid + i * NTHREADS;
    int hrow = idx / 16, q = idx % 16;
    float4 v = *(const float4*)(w0 + hrow * INF + q * 4);
    wl[(q * 4 + 0) * HID + hrow] = v.x;
    wl[(q * 4 + 1) * HID + hrow] = v.y;
    wl[(q * 4 + 2) * HID + hrow] = v.z;
    wl[(q * 4 + 3) * HID + hrow] = v.w;
  }
  int r0 = blockIdx.x * 64;
#pragma unroll
  for (int i = 0; i < 4; ++i) {     // x tile: 64x64 = 1024 float4
    int idx = tid + i * NTHREADS;
    int r = idx / 16, q = idx % 16;
    int gr = r0 + r;
    float4 v = make_float4(0.f, 0.f, 0.f, 0.f);
    if (gr < n) v = *(const float4*)(x + (size_t)gr * INF + q * 4);
    xT[(q * 4 + 0) * 68 + r] = v.x;
    xT[(q * 4 + 1) * 68 + r] = v.y;
    xT[(q * 4 + 2) * 68 + r] = v.z;
    xT[(q * 4 + 3) * 68 + r] = v.w;
  }
  __syncthreads();
  int rg = tid & 15, cg = tid >> 4;
  float acc[4][6];
#pragma unroll
  for (int i = 0; i < 4; ++i)
#pragma unroll
    for (int j = 0; j < 6; ++j) acc[i][j] = 0.f;
#pragma unroll 4
  for (int k = 0; k < INF; ++k) {
    float4 s4 = *(const float4*)(xT + k * 68 + rg * 4);
    const float2* w2 = (const float2*)(wl + k * HID + cg * 6);
    float2 wa = w2[0], wb = w2[1], wc = w2[2];
    float wv[6] = {wa.x, wa.y, wb.x, wb.y, wc.x, wc.y};
    float sv[4] = {s4.x, s4.y, s4.z, s4.w};
#pragma unroll
    for (int i = 0; i < 4; ++i)
#pragma unroll
      for (int j = 0; j < 6; ++j) acc[i][j] = fmaf(sv[i], wv[j], acc[i][j]);
  }
  float bb[6];
#pragma unroll
  for (int j = 0; j < 6; ++j) bb[j] = b0[cg * 6 + j];
#pragma unroll
  for (int i = 0; i < 4; ++i) {
    int gr = r0 + rg * 4 + i;
    if (gr < n) {
      float r_[6];
#pragma unroll
      for (int j = 0; j < 6; ++j) r_[j] = fmaxf(acc[i][j] + bb[j], 0.f);
      float* o = x0f + (size_t)gr * HID + cg * 6;
#pragma unroll
      for (int j = 0; j < 6; ++j) o[j] = r_[j];
      unsigned* ob = (unsigned*)(hb0 + (size_t)gr * HID + cg * 6);
      ob[0] = pack2bf(r_[0], r_[1]);
      ob[1] = pack2bf(r_[2], r_[3]);
      ob[2] = pack2bf(r_[4], r_[5]);
    }
  }
}

// ------- SpMM + residual: s = 0.9*(A_hat h) + 0.1*x0 ------------------------
// half-wave per row; 32 lanes = 8 edge-slots x 4 feature-groups (24 feats each).
__global__ __launch_bounds__(NTHREADS) void k_spmm(
    const unsigned short* __restrict__ hin, const float* __restrict__ x0,
    float* __restrict__ sout, const int* __restrict__ rp,
    const int2* __restrict__ ev, int n) {
  __shared__ float red[8][8][100];
  int t = threadIdx.x;
  int hw = t >> 5;            // half-wave id 0..7 (one row each)
  int lane = t & 31;
  int eb = lane >> 2;         // edge slot 0..7
  int fg = lane & 3;          // feature group 0..3 (24 features)
  int r = blockIdx.x * 8 + hw;
  if (r >= n) r = n - 1;      // clamp: duplicate work, benign same-value write
  int e0 = rp[r], e1 = rp[r + 1];   // >= 1 edge always (self-loop)
  float acc[24];
#pragma unroll
  for (int j = 0; j < 24; ++j) acc[j] = 0.f;

  int idx0 = e0 + eb;
  bool ok = idx0 < e1;
  idx0 = ok ? idx0 : e1 - 1;
  int2 cv = ev[idx0];
  for (int base = e0; base < e1; base += 8) {
    int2 cur = cv;
    bool okc = ok;
    int nb = base + 8;
    if (nb < e1) {            // prefetch next batch of edges
      int i2 = nb + eb;
      ok = i2 < e1;
      i2 = ok ? i2 : e1 - 1;
      cv = ev[i2];
    }
    float v = okc ? __int_as_float(cur.y) : 0.f;
    const unsigned short* hc = hin + (size_t)cur.x * HID + fg * 24;
    ushort8_t p0 = *(const ushort8_t*)(hc);
    ushort8_t p1 = *(const ushort8_t*)(hc + 8);
    ushort8_t p2 = *(const ushort8_t*)(hc + 16);
#pragma unroll
    for (int j = 0; j < 8; ++j) acc[j]      = fmaf(v, bf2f(p0[j]), acc[j]);
#pragma unroll
    for (int j = 0; j < 8; ++j) acc[8 + j]  = fmaf(v, bf2f(p1[j]), acc[8 + j]);
#pragma unroll
    for (int j = 0; j < 8; ++j) acc[16 + j] = fmaf(v, bf2f(p2[j]), acc[16 + j]);
  }
  // partial sums -> LDS
  float* myr = &red[hw][eb][fg * 24];
#pragma unroll
  for (int j = 0; j < 6; ++j)
    *(float4*)(myr + j * 4) =
        make_float4(acc[j * 4], acc[j * 4 + 1], acc[j * 4 + 2], acc[j * 4 + 3]);
  __syncthreads();
  // lanes 0..23 of each half-wave: sum 8 edge-slot copies of 4 features each
  if (lane < 24) {
    float4 tot = *(const float4*)(&red[hw][0][lane * 4]);
#pragma unroll
    for (int b = 1; b < 8; ++b) {
      float4 p = *(const float4*)(&red[hw][b][lane * 4]);
      tot.x += p.x; tot.y += p.y; tot.z += p.z; tot.w += p.w;
    }
    size_t o = (size_t)r * HID + lane * 4;
    float4 xr = *(const float4*)(x0 + o);
    float4 s4;
    s4.x = 0.9f * tot.x + 0.1f * xr.x;
    s4.y = 0.9f * tot.y + 0.1f * xr.y;
    s4.z = 0.9f * tot.z + 0.1f * xr.z;
    s4.w = 0.9f * tot.w + 0.1f * xr.w;
    *(float4*)(sout + o) = s4;
  }
}

// -------- h' = relu((1-b)*s + b*(s @ w)), MFMA bf16, s fp32, 64 rows/block -----
// A = s (fp32 LDS -> bf16 regs), B = wT bf16 LDS. bf16 noise enters only through
// the beta-scaled matmul term (beta in [0.03,0.41]) -> damped.
__global__ __launch_bounds__(NTHREADS) void k_gemm(
    const float* __restrict__ s, const unsigned short* __restrict__ wT,
    unsigned short* __restrict__ hout, float omb, float beta, int n) {
  __shared__ float sT[64 * 100];          // [r][k] fp32, stride 100 (pad)
  __shared__ unsigned short wl[HID * 104]; // [f][k] bf16, stride 104 (pad)
  int tid = threadIdx.x;
  int r0 = blockIdx.x * 64;
  {  // stage s: thread -> (row = tid>>2, 24-feat chunk = tid&3)
    int r = tid >> 2, c = (tid & 3) * 24;
    int gr = r0 + r;
    const float* src = s + (size_t)gr * HID + c;
    float* dst = sT + r * 100 + c;
    if (gr < n) {
#pragma unroll
      for (int j = 0; j < 6; ++j) *(float4*)(dst + j * 4) = *(const float4*)(src + j * 4);
    } else {
#pragma unroll
      for (int j = 0; j < 6; ++j) *(float4*)(dst + j * 4) = make_float4(0.f, 0.f, 0.f, 0.f);
    }
  }
  {  // stage wT: 96x96 bf16 = 1152 ushort8
#pragma unroll
    for (int i = 0; i < 5; ++i) {
      int idx = tid + i * NTHREADS;
      if (idx < 1152) {
        int f = idx / 12, c = (idx % 12) * 8;
        ushort8_t v = *(const ushort8_t*)(wT + f * HID + c);
        *(ushort8_t*)(wl + f * 104 + c) = v;
      }
    }
  }
  __syncthreads();
  int lane = tid & 63, wave = tid >> 6;
  int l15 = lane & 15;      // A-row / B-col / C-col
  int kg = lane >> 4;       // k-group 0..3
  f32x4_t acc[6];
#pragma unroll
  for (int i = 0; i < 6; ++i) acc[i] = (f32x4_t)(0.f);
#pragma unroll
  for (int kt = 0; kt < 3; ++kt) {
    const float* ap = sT + (wave * 16 + l15) * 100 + kt * 32 + kg * 8;
    float4 a0 = *(const float4*)(ap);
    float4 a1 = *(const float4*)(ap + 4);
    union { short8_t s8; unsigned u[4]; } A;
    A.u[0] = pack2bf(a0.x, a0.y);
    A.u[1] = pack2bf(a0.z, a0.w);
    A.u[2] = pack2bf(a1.x, a1.y);
    A.u[3] = pack2bf(a1.z, a1.w);
#pragma unroll
    for (int ft = 0; ft < 6; ++ft) {
      short8_t B = *(const short8_t*)(wl + (ft * 16 + l15) * 104 + kt * 32 + kg * 8);
      acc[ft] = __builtin_amdgcn_mfma_f32_16x16x32_bf16(A.s8, B, acc[ft], 0, 0, 0);
    }
  }
  // epilogue: C layout col = lane&15, row = (lane>>4)*4 + j   [m89-verified]
#pragma unroll
  for (int ft = 0; ft < 6; ++ft) {
    int col = ft * 16 + l15;
#pragma unroll
    for (int j = 0; j < 4; ++j) {
      int rl = wave * 16 + kg * 4 + j;
      int gr = r0 + rl;
      float sv = sT[rl * 100 + col];
      float o = fmaxf(omb * sv + beta * acc[ft][j], 0.f);
      if (gr < n) hout[(size_t)gr * HID + col] = f2bf(o);
    }
  }
}

// ---------------- out = h @ w1^T + b1  (h is bf16) ----------------
__global__ __launch_bounds__(NTHREADS) void k_lin1(
    const unsigned short* __restrict__ h, const float* __restrict__ w1,
    const float* __restrict__ b1, float* __restrict__ out, int n) {
  __shared__ float hT[HID * 68];    // [k][r]
  __shared__ float w1l[HID * OUTF]; // [k][o]
  int tid = threadIdx.x;
#pragma unroll
  for (int i = 0; i < 6; ++i) {     // w1: 16x96 = 1536 floats
    int idx = tid + i * NTHREADS;
    int o = idx / HID, k = idx % HID;
    w1l[k * OUTF + o] = w1[idx];
  }
  int r0 = blockIdx.x * 64;
#pragma unroll
  for (int i = 0; i < 3; ++i) {     // h tile: 64x96 bf16 = 768 ushort8
    int idx = tid + i * NTHREADS;
    int r = idx / 12, q = idx % 12;
    int gr = r0 + r;
    ushort8_t v = (ushort8_t)0;
    if (gr < n) v = *(const ushort8_t*)(h + (size_t)gr * HID + q * 8);
#pragma unroll
    for (int j = 0; j < 8; ++j) hT[(q * 8 + j) * 68 + r] = bf2f(v[j]);
  }
  __syncthreads();
  int r = tid & 63, og = tid >> 6;
  float acc[4] = {0.f, 0.f, 0.f, 0.f};
#pragma unroll 4
  for (int k = 0; k < HID; ++k) {
    float s = hT[k * 68 + r];
    float4 w4 = *(const float4*)(w1l + k * OUTF + og * 4);
    acc[0] = fmaf(s, w4.x, acc[0]);
    acc[1] = fmaf(s, w4.y, acc[1]);
    acc[2] = fmaf(s, w4.z, acc[2]);
    acc[3] = fmaf(s, w4.w, acc[3]);
  }
  int gr = r0 + r;
  if (gr < n) {
    float* op = out + (size_t)gr * OUTF + og * 4;
#pragma unroll
    for (int j = 0; j < 4; ++j) op[j] = acc[j] + b1[og * 4 + j];
  }
}

extern "C" void kernel_launch(void* const* d_in, const int* in_sizes, int n_in,
                              void* d_out, int out_size, void* d_ws, size_t ws_size,
                              hipStream_t stream) {
  const float* x  = (const float*)d_in[0];
  const int*   ei = (const int*)d_in[1];     // [2][E]: rows then cols
  const float* w0 = (const float*)d_in[2];
  const float* b0 = (const float*)d_in[3];
  const float* w1 = (const float*)d_in[4];
  const float* b1 = (const float*)d_in[5];
  const float* cw = (const float*)d_in[6];
  int n = in_sizes[0] / INF;    // 50000
  int e = in_sizes[1] / 2;      // 800000
  const int* row = ei;
  const int* col = ei + e;

  char* ws = (char*)d_ws;
  size_t off = 0;
  auto alloc = [&](size_t bytes) -> void* {
    void* p = (void*)(ws + off);
    off += (bytes + 255) & ~(size_t)255;
    return p;
  };
  float*          x0f = (float*)alloc((size_t)n * HID * 4);
  float*          sbuf= (float*)alloc((size_t)n * HID * 4);
  unsigned short* hbA = (unsigned short*)alloc((size_t)n * HID * 2);
  unsigned short* hbB = (unsigned short*)alloc((size_t)n * HID * 2);
  unsigned short* wTb = (unsigned short*)alloc((size_t)NLAYERS * HID * HID * 2);
  int*   deg  = (int*)alloc((size_t)n * 4);
  float* dis  = (float*)alloc((size_t)n * 4);
  float* sv   = (float*)alloc((size_t)n * 4);
  int*   cnt  = (int*)alloc((size_t)n * 4);
  int*   cur  = (int*)alloc((size_t)n * 4);
  int*   rp   = (int*)alloc((size_t)(n + 1) * 4);
  int2*  ev   = (int2*)alloc((size_t)(e + n) * 8);  // + self-loop slots
  int*   bsum = (int*)alloc(1024 * 4);
  (void)ws_size; (void)n_in; (void)out_size;

  int nb  = (n + NTHREADS - 1) / NTHREADS;   // 196
  int ebl = (e + NTHREADS - 1) / NTHREADS;   // 3125
  int r64 = (n + 63) / 64;                   // 782

  k_init<<<nb, NTHREADS, 0, stream>>>(deg, cnt, cur, n);
  k_count<<<ebl, NTHREADS, 0, stream>>>(row, col, deg, cnt, e);
  k_dis<<<nb, NTHREADS, 0, stream>>>(deg, dis, sv, n);
  k_scan1<<<nb, NTHREADS, 0, stream>>>(cnt, rp, bsum, n);
  k_scan2<<<1, NTHREADS, 0, stream>>>(bsum, nb);
  k_scan3<<<nb, NTHREADS, 0, stream>>>(rp, bsum, n, e + n);
  k_self<<<nb, NTHREADS, 0, stream>>>(rp, sv, ev, n);
  k_scatter<<<ebl, NTHREADS, 0, stream>>>(row, col, rp, cur, dis, ev, e);
  k_wprime<<<dim3(36, NLAYERS), NTHREADS, 0, stream>>>(cw, wTb);
  k_lin0<<<r64, NTHREADS, 0, stream>>>(x, w0, b0, x0f, hbA, n);

  const unsigned short* hin = hbA;
  for (int l = 0; l < NLAYERS; ++l) {
    unsigned short* hout = (l & 1) ? hbA : hbB;
    float beta = logf(0.5f / (float)(l + 1) + 1.0f);
    k_spmm<<<(n + 7) / 8, NTHREADS, 0, stream>>>(hin, x0f, sbuf, rp, ev, n);
    k_gemm<<<r64, NTHREADS, 0, stream>>>(sbuf, wTb + (size_t)l * HID * HID,
                                         hout, 1.0f - beta, beta, n);
    hin = hout;
  }
  k_lin1<<<r64, NTHREADS, 0, stream>>>(hin, w1, b1, (float*)d_out, n);
}